// Round 8
// baseline (260.344 us; speedup 1.0000x reference)
//
#include <hip/hip_runtime.h>
#include <hip/hip_bf16.h>

// Shapes (fixed): B=4, Q=K=1024, D=256, H=8, C=32. World = fp32 (proven r2-7).
// MFMA mappings HW-proven (r6/r7): A[m=lane&15][k=quad*8+j],
// B[k=quad*8+j][n=lane&15], C/D col=lane&15, row=quad*4+reg.
//
// Round 8: barrier-free attention. K's B-frag is a contiguous row chunk of
// khb -> direct global load. V is stored PRE-TRANSPOSED by proj_mfma
// (vhT[bh][c][kpos]) so PV's B-frag is also a direct global load. Only the
// per-wave P C->A layout LDS round-trip remains (lgkmcnt-guarded, r7-proven).
//
// Workspace (byte offsets):
//   wt   5x[256][256] bf16 @ 0        (wq,wk,wv,wg,wo transposed wt[n][k])
//   qhb  [B,H,Q,C]   bf16 @ 655360   (q/sqrt(C))
//   khb  [B,H,K,C]   bf16 @ 2752512
//   vhT  [B,H,C,K]   bf16 @ 4849664  (v transposed per head)
//   og   [B,Q,256]   bf16 @ 6946816
//   gws  [B,Q,256]   fp32 @ 9043968

typedef short bf16x8 __attribute__((ext_vector_type(8)));
typedef float f32x4 __attribute__((ext_vector_type(4)));

__device__ __forceinline__ unsigned short f2bf(float f) {
  __hip_bfloat16 hb = __float2bfloat16(f);
  return *reinterpret_cast<const unsigned short*>(&hb);
}

// ------------- Kernel 0: transpose + fp32->bf16 convert weights ----------
__global__ __launch_bounds__(256) void transpose_conv(
    const float* __restrict__ wq, const float* __restrict__ wk,
    const float* __restrict__ wv, const float* __restrict__ wg,
    const float* __restrict__ wo, unsigned short* __restrict__ wt) {
  __shared__ float t[64][65];
  const int widx = blockIdx.x >> 4;
  const int tile = blockIdx.x & 15;
  const float* src = widx == 0 ? wq : widx == 1 ? wk
                     : widx == 2 ? wv : widx == 3 ? wg : wo;
  unsigned short* dst = wt + widx * 65536;
  const int r0 = (tile >> 2) * 64, c0 = (tile & 3) * 64;
  const int tr = threadIdx.x >> 4;
  const int tc4 = (threadIdx.x & 15) * 4;
#pragma unroll
  for (int i = 0; i < 4; ++i) {
    const float4 u = *reinterpret_cast<const float4*>(
        src + (size_t)(r0 + tr + i * 16) * 256 + c0 + tc4);
    t[tr + i * 16][tc4 + 0] = u.x;
    t[tr + i * 16][tc4 + 1] = u.y;
    t[tr + i * 16][tc4 + 2] = u.z;
    t[tr + i * 16][tc4 + 3] = u.w;
  }
  __syncthreads();
#pragma unroll
  for (int i = 0; i < 4; ++i) {
    const int rr = tr + i * 16;
    ushort4 o;
    o.x = f2bf(t[tc4 + 0][rr]);
    o.y = f2bf(t[tc4 + 1][rr]);
    o.z = f2bf(t[tc4 + 2][rr]);
    o.w = f2bf(t[tc4 + 3][rr]);
    *reinterpret_cast<ushort4*>(dst + (size_t)(c0 + rr) * 256 + r0 + tc4) = o;
  }
}

// ------------- Kernel 1: input projections (MFMA) ------------------------
// grid (256, 2): x = 16-row m-tile, y = side (0: wq/wg, 1: wk/wv).
// side 1 writes khb row-major and V TRANSPOSED (vhT[bh][c][kpos]).
__global__ __launch_bounds__(256) void proj_mfma(
    const float* __restrict__ q_x, const float* __restrict__ kv_x,
    const unsigned short* __restrict__ wt, const float* __restrict__ bg,
    unsigned short* __restrict__ qhb, unsigned short* __restrict__ khb,
    unsigned short* __restrict__ vhT, float* __restrict__ gws) {
  const int side = blockIdx.y;
  const int m0 = blockIdx.x * 16;
  const int lane = threadIdx.x & 63;
  const int n0 = (threadIdx.x >> 6) * 64;
  const int mrow = lane & 15;
  const int quad = lane >> 4;
  const float* X = side ? kv_x : q_x;
  const unsigned short* W0 = wt + (side ? 1 : 0) * 65536;  // wk : wq
  const unsigned short* W1 = wt + (side ? 2 : 3) * 65536;  // wv : wg
  f32x4 acc0[4], acc1[4];
  const f32x4 z = {0.f, 0.f, 0.f, 0.f};
#pragma unroll
  for (int nt = 0; nt < 4; ++nt) { acc0[nt] = z; acc1[nt] = z; }

  for (int k0 = 0; k0 < 256; k0 += 32) {
    const size_t abase = (size_t)(m0 + mrow) * 256 + k0 + quad * 8;
    const float4 a0 = *reinterpret_cast<const float4*>(X + abase);
    const float4 a1 = *reinterpret_cast<const float4*>(X + abase + 4);
    bf16x8 a;
    a[0] = (short)f2bf(a0.x); a[1] = (short)f2bf(a0.y);
    a[2] = (short)f2bf(a0.z); a[3] = (short)f2bf(a0.w);
    a[4] = (short)f2bf(a1.x); a[5] = (short)f2bf(a1.y);
    a[6] = (short)f2bf(a1.z); a[7] = (short)f2bf(a1.w);
#pragma unroll
    for (int nt = 0; nt < 4; ++nt) {
      const size_t wrow = (size_t)(n0 + nt * 16 + mrow) * 256 + k0 + quad * 8;
      const bf16x8 b0 = *reinterpret_cast<const bf16x8*>(W0 + wrow);
      const bf16x8 b1 = *reinterpret_cast<const bf16x8*>(W1 + wrow);
      acc0[nt] = __builtin_amdgcn_mfma_f32_16x16x32_bf16(a, b0, acc0[nt], 0, 0, 0);
      acc1[nt] = __builtin_amdgcn_mfma_f32_16x16x32_bf16(a, b1, acc1[nt], 0, 0, 0);
    }
  }

  const int b = m0 >> 10;
#pragma unroll
  for (int nt = 0; nt < 4; ++nt) {
    const int n = n0 + nt * 16 + mrow;  // output col
    const int h = n >> 5, c = n & 31;
    const int bh = b * 8 + h;
    const float bgv = (side == 0) ? bg[n] : 0.f;
#pragma unroll
    for (int r = 0; r < 4; ++r) {
      const int row = m0 + quad * 4 + r;
      const int qp = row & 1023;
      if (side == 0) {
        qhb[((size_t)bh * 1024 + qp) * 32 + c] =
            f2bf(acc0[nt][r] * 0.17677669529663689f);  // 1/sqrt(32)
        const float zz = acc1[nt][r] + bgv;
        gws[(size_t)row * 256 + n] = 1.0f / (1.0f + __expf(-zz));
      } else {
        khb[((size_t)bh * 1024 + qp) * 32 + c] = f2bf(acc0[nt][r]);
        vhT[((size_t)bh * 32 + c) * 1024 + qp] = f2bf(acc1[nt][r]);
      }
    }
  }
}

// ------------- Kernel 2: barrier-free MFMA flash attention + gate --------
// grid 512 = B*H*(Q/64); 4 waves, wave wv owns q-rows (x&15)*64+wv*16..+15.
// Per K-tile: QK^T = 4 MFMAs (C preloaded with bias_pair+bias_mask; K
// B-frags = direct 16B global loads), online softmax (16-lane shfl groups),
// P -> per-wave LDS (lgkmcnt-guarded) -> A-frag, PV = 4 MFMAs (V B-frags =
// direct 16B global loads from vhT). NO __syncthreads anywhere.
__global__ __launch_bounds__(256) void attn_mfma(
    const unsigned short* __restrict__ qhb,
    const unsigned short* __restrict__ khb,
    const unsigned short* __restrict__ vhT,
    const float* __restrict__ bias_mask,
    const float* __restrict__ bias_pair,
    const float* __restrict__ gws, unsigned short* __restrict__ og) {
  __shared__ unsigned short ps[4 * 16 * 72];  // per-wave 16x64 P (stride 72)
  const int x = blockIdx.x;
  const int b = x >> 7, h = (x >> 4) & 7;
  const int tid = threadIdx.x;
  const int wv = tid >> 6, lane = tid & 63, quad = lane >> 4, lr = lane & 15;
  const int bh = b * 8 + h;
  const int q0 = (x & 15) * 64 + wv * 16;  // this wave's 16 q-rows
  unsigned short* psw = ps + wv * 16 * 72;

  // Q A-frag held in regs for all 16 K-tiles.
  const bf16x8 aq = *reinterpret_cast<const bf16x8*>(
      qhb + ((size_t)bh * 1024 + q0 + lr) * 32 + quad * 8);

  float m[4], l[4];
  f32x4 oa[2];
  const f32x4 zero4 = {0.f, 0.f, 0.f, 0.f};
  oa[0] = zero4; oa[1] = zero4;
#pragma unroll
  for (int r = 0; r < 4; ++r) { m[r] = -3e30f; l[r] = 0.f; }

  const float* bp = bias_pair + ((size_t)bh * 1024 + q0) * 1024;
  const float* bm = bias_mask + (size_t)b * 1024;
  const unsigned short* kbase = khb + (size_t)bh * 32768;
  const unsigned short* vbase = vhT + (size_t)bh * 32768;

  for (int kt = 0; kt < 16; ++kt) {
    const int kk0 = kt * 64;

    // ---- scores: C = bias_pair + bias_mask, then += Q K^T ----
    f32x4 s[4];
#pragma unroll
    for (int nt = 0; nt < 4; ++nt) {
      const int kcol = kk0 + 16 * nt + lr;
      const float mk = bm[kcol];
#pragma unroll
      for (int r = 0; r < 4; ++r)
        s[nt][r] = bp[(size_t)(quad * 4 + r) * 1024 + kcol] + mk;
    }
#pragma unroll
    for (int nt = 0; nt < 4; ++nt) {
      const bf16x8 bk = *reinterpret_cast<const bf16x8*>(
          kbase + (size_t)(kk0 + 16 * nt + lr) * 32 + quad * 8);
      s[nt] = __builtin_amdgcn_mfma_f32_16x16x32_bf16(aq, bk, s[nt], 0, 0, 0);
    }

    // ---- online softmax (rows quad*4+r; reduce across the 16 lr lanes) --
#pragma unroll
    for (int r = 0; r < 4; ++r) {
      float mx = fmaxf(fmaxf(s[0][r], s[1][r]), fmaxf(s[2][r], s[3][r]));
      mx = fmaxf(mx, __shfl_xor(mx, 1));
      mx = fmaxf(mx, __shfl_xor(mx, 2));
      mx = fmaxf(mx, __shfl_xor(mx, 4));
      mx = fmaxf(mx, __shfl_xor(mx, 8));
      const float mn = fmaxf(m[r], mx);
      const float alpha = __expf(m[r] - mn);
      float rs = 0.f;
#pragma unroll
      for (int nt = 0; nt < 4; ++nt) {
        s[nt][r] = __expf(s[nt][r] - mn);
        rs += s[nt][r];
      }
      rs += __shfl_xor(rs, 1);
      rs += __shfl_xor(rs, 2);
      rs += __shfl_xor(rs, 4);
      rs += __shfl_xor(rs, 8);
      l[r] = l[r] * alpha + rs;
      m[r] = mn;
      oa[0][r] *= alpha;
      oa[1][r] *= alpha;
      const int ri = quad * 4 + r;
#pragma unroll
      for (int nt = 0; nt < 4; ++nt)
        psw[ri * 72 + 16 * nt + lr] = f2bf(s[nt][r]);
    }
    // psw is wave-private: drain LDS writes, block hoisting of the reads.
    asm volatile("s_waitcnt lgkmcnt(0)" ::: "memory");

    // ---- PV: A = P (LDS), B = V^T rows (direct global 16B loads) ----
#pragma unroll
    for (int k0i = 0; k0i < 2; ++k0i) {
      const bf16x8 ap = *reinterpret_cast<const bf16x8*>(
          psw + lr * 72 + k0i * 32 + quad * 8);
#pragma unroll
      for (int nt2 = 0; nt2 < 2; ++nt2) {
        const bf16x8 bv = *reinterpret_cast<const bf16x8*>(
            vbase + (size_t)(nt2 * 16 + lr) * 1024 + kk0 + k0i * 32 + quad * 8);
        oa[nt2] = __builtin_amdgcn_mfma_f32_16x16x32_bf16(ap, bv, oa[nt2], 0, 0, 0);
      }
    }
  }

  // ---- normalize, gate, store bf16 ----
#pragma unroll
  for (int r = 0; r < 4; ++r) {
    const int qr = q0 + quad * 4 + r;
    const float inv = 1.0f / l[r];
    const size_t base = ((size_t)b * 1024 + qr) * 256 + h * 32;
#pragma unroll
    for (int nt2 = 0; nt2 < 2; ++nt2) {
      const int c = nt2 * 16 + lr;
      og[base + c] = f2bf(oa[nt2][r] * inv * gws[base + c]);
    }
  }
}

// ------------- Kernel 3: output projection (MFMA), fp32 out --------------
__global__ __launch_bounds__(256) void outproj_mfma(
    const unsigned short* __restrict__ og,
    const unsigned short* __restrict__ wt,
    const float* __restrict__ bo, float* __restrict__ out) {
  const int m0 = blockIdx.x * 16;
  const int lane = threadIdx.x & 63;
  const int n0 = (threadIdx.x >> 6) * 64;
  const int mrow = lane & 15;
  const int quad = lane >> 4;
  const unsigned short* W = wt + 4 * 65536;  // wo^T
  f32x4 acc[4];
  const f32x4 z = {0.f, 0.f, 0.f, 0.f};
#pragma unroll
  for (int nt = 0; nt < 4; ++nt) acc[nt] = z;

  for (int k0 = 0; k0 < 256; k0 += 32) {
    const bf16x8 a = *reinterpret_cast<const bf16x8*>(
        og + (size_t)(m0 + mrow) * 256 + k0 + quad * 8);
#pragma unroll
    for (int nt = 0; nt < 4; ++nt) {
      const bf16x8 b = *reinterpret_cast<const bf16x8*>(
          W + (size_t)(n0 + nt * 16 + mrow) * 256 + k0 + quad * 8);
      acc[nt] = __builtin_amdgcn_mfma_f32_16x16x32_bf16(a, b, acc[nt], 0, 0, 0);
    }
  }

#pragma unroll
  for (int nt = 0; nt < 4; ++nt) {
    const int n = n0 + nt * 16 + mrow;
    const float bov = bo[n];
#pragma unroll
    for (int r = 0; r < 4; ++r) {
      const int row = m0 + quad * 4 + r;
      out[(size_t)row * 256 + n] = acc[nt][r] + bov;
    }
  }
}

extern "C" void kernel_launch(void* const* d_in, const int* in_sizes, int n_in,
                              void* d_out, int out_size, void* d_ws,
                              size_t ws_size, hipStream_t stream) {
  (void)in_sizes; (void)n_in; (void)out_size; (void)ws_size;
  const float* q_x = (const float*)d_in[0];
  const float* kv_x = (const float*)d_in[1];
  const float* bias_mask = (const float*)d_in[2];
  const float* bias_pair = (const float*)d_in[3];
  const float* wq = (const float*)d_in[4];
  const float* wk = (const float*)d_in[5];
  const float* wv = (const float*)d_in[6];
  const float* wg = (const float*)d_in[7];
  const float* bg = (const float*)d_in[8];
  const float* wo = (const float*)d_in[9];
  const float* bo = (const float*)d_in[10];

  char* wsb = (char*)d_ws;
  unsigned short* wt  = (unsigned short*)(wsb);            // 640 KB
  unsigned short* qhb = (unsigned short*)(wsb + 655360);   // 2 MB
  unsigned short* khb = (unsigned short*)(wsb + 2752512);  // 2 MB
  unsigned short* vhT = (unsigned short*)(wsb + 4849664);  // 2 MB
  unsigned short* og  = (unsigned short*)(wsb + 6946816);  // 2 MB
  float* gws          = (float*)(wsb + 9043968);           // 4 MB

  transpose_conv<<<80, 256, 0, stream>>>(wq, wk, wv, wg, wo, wt);
  proj_mfma<<<dim3(256, 2), 256, 0, stream>>>(q_x, kv_x, wt, bg, qhb, khb,
                                              vhT, gws);
  attn_mfma<<<512, 256, 0, stream>>>(qhb, khb, vhT, bias_mask, bias_pair, gws,
                                     og);
  outproj_mfma<<<256, 256, 0, stream>>>(og, wt, bo, (float*)d_out);
}